// Round 2
// baseline (979.723 us; speedup 1.0000x reference)
//
#include <hip/hip_runtime.h>

typedef unsigned short u16;
typedef __bf16 bf16x8 __attribute__((ext_vector_type(8)));
typedef short  s16x8  __attribute__((ext_vector_type(8)));
typedef float  f32x4  __attribute__((ext_vector_type(4)));

// --- builtin operand-type hedge: pick whichever vector type the bf16 MFMA
// builtin accepts on this toolchain.
template <bool B, class T, class F> struct cond_t { using type = T; };
template <class T, class F> struct cond_t<false, T, F> { using type = F; };
template <typename T>
__device__ auto probe_mfma(int)
    -> decltype(__builtin_amdgcn_mfma_f32_16x16x32_bf16(T{}, T{}, f32x4{}, 0, 0, 0), (char)0);
template <typename T> __device__ short probe_mfma(...);
using frag_t = typename cond_t<sizeof(probe_mfma<bf16x8>(0)) == 1, bf16x8, s16x8>::type;
#define MFMA(a, b, c) __builtin_amdgcn_mfma_f32_16x16x32_bf16((a), (b), (c), 0, 0, 0)

__device__ __forceinline__ float bf2f(u16 u) {
  unsigned int x = ((unsigned int)u) << 16; float f; __builtin_memcpy(&f, &x, 4); return f;
}
__device__ __forceinline__ u16 f2bf(float f) {
  unsigned int x; __builtin_memcpy(&x, &f, 4);
  x += 0x7fffu + ((x >> 16) & 1u);  // RNE
  return (u16)(x >> 16);
}
__device__ __forceinline__ float gelu_f(float x) {
  return 0.5f * x * (1.0f + erff(x * 0.70710678118654752440f));
}

// ---------- weight transpose+cast: dst[b][n][k] (bf16) = src[b][k][n] (f32) ----------
__global__ __launch_bounds__(256) void k_tr(const float* __restrict__ src, u16* __restrict__ dst,
                                            int batch, int K, int N) {
  long KN = (long)K * N;
  long total = (long)batch * KN;
  for (long i = (long)blockIdx.x * blockDim.x + threadIdx.x; i < total;
       i += (long)gridDim.x * blockDim.x) {
    long b = i / KN; long rem = i - b * KN;
    long n = rem / K; long k = rem - n * K;
    dst[i] = f2bf(src[b * KN + k * N + n]);
  }
}

// ---------- K1: LayerNorm(x) -> xn (bf16, ws) ; sigmoid gates -> f32 (ws) ----------
__global__ __launch_bounds__(256) void k1_ln_gate(
    const float* __restrict__ x, const float* __restrict__ ng, const float* __restrict__ nb,
    const float* __restrict__ gW, const float* __restrict__ gb,
    u16* __restrict__ xn, float* __restrict__ gate) {
  const int lane = threadIdx.x & 63;
  const long t = (long)blockIdx.x * 4 + (threadIdx.x >> 6);
  float4 a0 = *(const float4*)(x + t * 512 + lane * 8);
  float4 a1 = *(const float4*)(x + t * 512 + lane * 8 + 4);
  float f[8] = {a0.x, a0.y, a0.z, a0.w, a1.x, a1.y, a1.z, a1.w};
  float s = 0.f, ss = 0.f;
#pragma unroll
  for (int j = 0; j < 8; j++) { s += f[j]; ss += f[j] * f[j]; }
#pragma unroll
  for (int m = 1; m < 64; m <<= 1) { s += __shfl_xor(s, m); ss += __shfl_xor(ss, m); }
  const float mean = s * (1.0f / 512.0f);
  const float rstd = rsqrtf(ss * (1.0f / 512.0f) - mean * mean + 1e-5f);
  float xf[8];
  union { uint4 q; u16 u[8]; } st;
#pragma unroll
  for (int j = 0; j < 8; j++) {
    xf[j] = (f[j] - mean) * rstd * ng[lane * 8 + j] + nb[lane * 8 + j];
    st.u[j] = f2bf(xf[j]);
  }
  *(uint4*)(xn + t * 512 + lane * 8) = st.q;
  for (int h = 0; h < 4; h++) {
    float p = 0.f;
#pragma unroll
    for (int j = 0; j < 8; j++) p += xf[j] * gW[h * 512 + lane * 8 + j];
#pragma unroll
    for (int m = 1; m < 64; m <<= 1) p += __shfl_xor(p, m);
    if (lane == 0) gate[t * 4 + h] = 1.0f / (1.0f + expf(-(p + gb[h])));
  }
}

// ---------- K2: per (64-token tile, head) fused head pipeline ----------
__global__ __launch_bounds__(256, 1) void k2_head(
    const u16* __restrict__ xn, const u16* __restrict__ hW1t, const float* __restrict__ hb1,
    const float* __restrict__ hlng, const float* __restrict__ hlnb,
    const u16* __restrict__ hW2t, const float* __restrict__ hb2,
    const float* __restrict__ attr, const u16* __restrict__ dynT,
    const float* __restrict__ gate, float* __restrict__ outC) {
  __shared__ __align__(16) char smem[61440];
  u16* sA  = (u16*)(smem);               // [64][40]   phase1 A tile
  u16* sB  = (u16*)(smem + 5120);        // [256][40]  phase1 B tile
  u16* sH  = (u16*)(smem);               // [64][264]  phase2 A source (overlaps dead sA/sB)
  u16* sB2 = (u16*)(smem + 33792);       // [128][40]  phase2/3 B tiles
  u16* sSt = (u16*)(smem + 44032);       // [64][136]  phase3 A source (state bf16)
  float* sAttrF = (float*)(smem);        // [8][128]   phase3 (overlaps dead sH)
  float* sA2    = (float*)(smem + 4096); // [8]

  const int tid = threadIdx.x;
  const int lane = tid & 63, wv = tid >> 6, q = lane >> 4, l15 = lane & 15;
  const int h = blockIdx.y;
  const long t0 = (long)blockIdx.x * 64;
  const f32x4 vz = {0.f, 0.f, 0.f, 0.f};

  f32x4 acc[16];
#pragma unroll
  for (int i = 0; i < 16; i++) acc[i] = vz;
  const int arow = tid >> 2, ako = (tid & 3) * 8;

  for (int kb = 0; kb < 512; kb += 32) {
    *(uint4*)&sA[arow * 40 + ako] = *(const uint4*)&xn[(t0 + arow) * 512 + kb + ako];
#pragma unroll
    for (int i = 0; i < 4; i++) {
      int c = tid + 256 * i, r = c >> 2, ko = (c & 3) * 8;
      *(uint4*)&sB[r * 40 + ko] = *(const uint4*)&hW1t[((long)h * 256 + r) * 512 + kb + ko];
    }
    __syncthreads();
    frag_t af = *(const frag_t*)&sA[(wv * 16 + l15) * 40 + q * 8];
#pragma unroll
    for (int nt = 0; nt < 16; nt++) {
      frag_t bf = *(const frag_t*)&sB[(nt * 16 + l15) * 40 + q * 8];
      acc[nt] = MFMA(af, bf, acc[nt]);
    }
    __syncthreads();
  }

  {  // bias + LN(256) + gelu -> sH (bf16)
    float bb[16], cg[16], cb[16];
#pragma unroll
    for (int nt = 0; nt < 16; nt++) {
      int col = nt * 16 + l15;
      bb[nt] = hb1[h * 256 + col];
      cg[nt] = hlng[h * 256 + col];
      cb[nt] = hlnb[h * 256 + col];
    }
#pragma unroll
    for (int r = 0; r < 4; r++) {
      float s = 0.f, ss = 0.f;
#pragma unroll
      for (int nt = 0; nt < 16; nt++) { float v = acc[nt][r] + bb[nt]; s += v; ss += v * v; }
#pragma unroll
      for (int m = 1; m < 16; m <<= 1) { s += __shfl_xor(s, m); ss += __shfl_xor(ss, m); }
      float mean = s * (1.f / 256.f);
      float rstd = rsqrtf(ss * (1.f / 256.f) - mean * mean + 1e-5f);
      int row = wv * 16 + q * 4 + r;
#pragma unroll
      for (int nt = 0; nt < 16; nt++) {
        float v = (acc[nt][r] + bb[nt] - mean) * rstd * cg[nt] + cb[nt];
        sH[row * 264 + nt * 16 + l15] = f2bf(gelu_f(v));
      }
    }
  }
  __syncthreads();

  f32x4 acc2[8];
#pragma unroll
  for (int i = 0; i < 8; i++) acc2[i] = vz;
  for (int kb = 0; kb < 256; kb += 32) {
#pragma unroll
    for (int i = 0; i < 2; i++) {
      int c = tid + 256 * i, r = c >> 2, ko = (c & 3) * 8;
      *(uint4*)&sB2[r * 40 + ko] = *(const uint4*)&hW2t[((long)h * 128 + r) * 256 + kb + ko];
    }
    __syncthreads();
    frag_t af = *(const frag_t*)&sH[(wv * 16 + l15) * 264 + kb + q * 8];
#pragma unroll
    for (int nt = 0; nt < 8; nt++) {
      frag_t bf = *(const frag_t*)&sB2[(nt * 16 + l15) * 40 + q * 8];
      acc2[nt] = MFMA(af, bf, acc2[nt]);
    }
    __syncthreads();
  }
#pragma unroll
  for (int nt = 0; nt < 8; nt++) {
    float b2 = hb2[h * 128 + nt * 16 + l15];
#pragma unroll
    for (int r = 0; r < 4; r++) acc2[nt][r] += b2;
  }

  // state -> sSt (bf16 A-source for dyn GEMM); attractors -> LDS f32
#pragma unroll
  for (int nt = 0; nt < 8; nt++)
#pragma unroll
    for (int r = 0; r < 4; r++)
      sSt[(wv * 16 + q * 4 + r) * 136 + nt * 16 + l15] = f2bf(acc2[nt][r]);
#pragma unroll
  for (int i = 0; i < 4; i++) { int c = tid + 256 * i; sAttrF[c] = attr[h * 1024 + c]; }
  __syncthreads();
  if (tid < 8) {
    float s = 0.f;
    for (int d = 0; d < 128; d++) { float v = sAttrF[tid * 128 + d]; s += v * v; }
    sA2[tid] = s;
  }
  __syncthreads();

  f32x4 dacc[8];
#pragma unroll
  for (int i = 0; i < 8; i++) dacc[i] = vz;
  for (int kb = 0; kb < 128; kb += 32) {
#pragma unroll
    for (int i = 0; i < 2; i++) {
      int c = tid + 256 * i, r = c >> 2, ko = (c & 3) * 8;
      *(uint4*)&sB2[r * 40 + ko] = *(const uint4*)&dynT[((long)h * 128 + r) * 128 + kb + ko];
    }
    __syncthreads();
    frag_t af = *(const frag_t*)&sSt[(wv * 16 + l15) * 136 + kb + q * 8];
#pragma unroll
    for (int nt = 0; nt < 8; nt++) {
      frag_t bf = *(const frag_t*)&sB2[(nt * 16 + l15) * 40 + q * 8];
      dacc[nt] = MFMA(af, bf, dacc[nt]);
    }
    __syncthreads();
  }

  const float dscale = 0.088388347648318447f;  // 1/sqrt(128)
#pragma unroll
  for (int r = 0; r < 4; r++) {
    const long t = t0 + wv * 16 + q * 4 + r;
    float s2v = 0.f;
#pragma unroll
    for (int nt = 0; nt < 8; nt++) s2v += acc2[nt][r] * acc2[nt][r];
#pragma unroll
    for (int m = 1; m < 16; m <<= 1) s2v += __shfl_xor(s2v, m);
    float lg[8]; float mx = -3.0e38f;
#pragma unroll
    for (int a = 0; a < 8; a++) {
      float sa = 0.f;
#pragma unroll
      for (int nt = 0; nt < 8; nt++) sa += acc2[nt][r] * sAttrF[a * 128 + nt * 16 + l15];
#pragma unroll
      for (int m = 1; m < 16; m <<= 1) sa += __shfl_xor(sa, m);
      float dist = sqrtf(fmaxf(s2v + sA2[a] - 2.0f * sa, 0.0f));
      lg[a] = -dist * dscale;
      mx = fmaxf(mx, lg[a]);
    }
    float den = 0.f;
#pragma unroll
    for (int a = 0; a < 8; a++) { lg[a] = expf(lg[a] - mx); den += lg[a]; }
    const float rden = 1.0f / den;
    const float g01 = gate[t * 4 + h] * 0.1f;
#pragma unroll
    for (int nt = 0; nt < 8; nt++) {
      int col = nt * 16 + l15;
      float ai = 0.f;
#pragma unroll
      for (int a = 0; a < 8; a++) ai += lg[a] * sAttrF[a * 128 + col];
      ai *= rden;
      float stv = acc2[nt][r];
      float ho = stv + g01 * (ai - stv + tanhf(dacc[nt][r]));
      outC[t * 512 + h * 128 + col] = ho;
    }
  }
}

// ---------- K3: o1 = gelu(LN(combined @ oW1 + ob1)) ; in-place on d_out (f32) ----------
__global__ __launch_bounds__(256, 1) void k3_mlp1(
    const float* __restrict__ inp, const u16* __restrict__ oW1t,
    const float* __restrict__ ob1, const float* __restrict__ olng, const float* __restrict__ olnb,
    float* __restrict__ outp) {
  __shared__ __align__(16) char smem[46080];
  u16* sA = (u16*)smem;            // [64][40]
  u16* sB = (u16*)(smem + 5120);   // [512][40]
  const int tid = threadIdx.x, lane = tid & 63, wv = tid >> 6, q = lane >> 4, l15 = lane & 15;
  const long t0 = (long)blockIdx.x * 64;
  const f32x4 vz = {0.f, 0.f, 0.f, 0.f};
  f32x4 acc[32];
#pragma unroll
  for (int i = 0; i < 32; i++) acc[i] = vz;
  const int arow = tid >> 2, ako = (tid & 3) * 8;
  for (int kb = 0; kb < 512; kb += 32) {
    {
      float4 v0 = *(const float4*)&inp[(t0 + arow) * 512 + kb + ako];
      float4 v1 = *(const float4*)&inp[(t0 + arow) * 512 + kb + ako + 4];
      union { uint4 qq; u16 u[8]; } pk;
      pk.u[0] = f2bf(v0.x); pk.u[1] = f2bf(v0.y); pk.u[2] = f2bf(v0.z); pk.u[3] = f2bf(v0.w);
      pk.u[4] = f2bf(v1.x); pk.u[5] = f2bf(v1.y); pk.u[6] = f2bf(v1.z); pk.u[7] = f2bf(v1.w);
      *(uint4*)&sA[arow * 40 + ako] = pk.qq;
    }
#pragma unroll
    for (int i = 0; i < 8; i++) {
      int c = tid + 256 * i, r = c >> 2, ko = (c & 3) * 8;
      *(uint4*)&sB[r * 40 + ko] = *(const uint4*)&oW1t[(long)r * 512 + kb + ko];
    }
    __syncthreads();
    frag_t af = *(const frag_t*)&sA[(wv * 16 + l15) * 40 + q * 8];
#pragma unroll
    for (int nt = 0; nt < 32; nt++) {
      frag_t bf = *(const frag_t*)&sB[(nt * 16 + l15) * 40 + q * 8];
      acc[nt] = MFMA(af, bf, acc[nt]);
    }
    __syncthreads();
  }
  float bb[32];
#pragma unroll
  for (int nt = 0; nt < 32; nt++) bb[nt] = ob1[nt * 16 + l15];
#pragma unroll
  for (int r = 0; r < 4; r++) {
    float s = 0.f, ss = 0.f;
#pragma unroll
    for (int nt = 0; nt < 32; nt++) { float v = acc[nt][r] + bb[nt]; s += v; ss += v * v; }
#pragma unroll
    for (int m = 1; m < 16; m <<= 1) { s += __shfl_xor(s, m); ss += __shfl_xor(ss, m); }
    float mean = s * (1.f / 512.f);
    float rstd = rsqrtf(ss * (1.f / 512.f) - mean * mean + 1e-5f);
    const long t = t0 + wv * 16 + q * 4 + r;
#pragma unroll
    for (int nt = 0; nt < 32; nt++) {
      int col = nt * 16 + l15;
      float v = (acc[nt][r] + bb[nt] - mean) * rstd * olng[col] + olnb[col];
      outp[t * 512 + col] = gelu_f(v);
    }
  }
}

// ---------- K4: out = xn + o1 @ oW2 + ob2 ; in-place on d_out (f32) ----------
__global__ __launch_bounds__(256, 1) void k4_mlp2(
    const float* __restrict__ inp, const u16* __restrict__ oW2t,
    const float* __restrict__ ob2, const u16* __restrict__ xn,
    float* __restrict__ outp) {
  __shared__ __align__(16) char smem[46080];
  u16* sA = (u16*)smem;
  u16* sB = (u16*)(smem + 5120);
  const int tid = threadIdx.x, lane = tid & 63, wv = tid >> 6, q = lane >> 4, l15 = lane & 15;
  const long t0 = (long)blockIdx.x * 64;
  const f32x4 vz = {0.f, 0.f, 0.f, 0.f};
  f32x4 acc[32];
#pragma unroll
  for (int i = 0; i < 32; i++) acc[i] = vz;
  const int arow = tid >> 2, ako = (tid & 3) * 8;
  for (int kb = 0; kb < 512; kb += 32) {
    {
      float4 v0 = *(const float4*)&inp[(t0 + arow) * 512 + kb + ako];
      float4 v1 = *(const float4*)&inp[(t0 + arow) * 512 + kb + ako + 4];
      union { uint4 qq; u16 u[8]; } pk;
      pk.u[0] = f2bf(v0.x); pk.u[1] = f2bf(v0.y); pk.u[2] = f2bf(v0.z); pk.u[3] = f2bf(v0.w);
      pk.u[4] = f2bf(v1.x); pk.u[5] = f2bf(v1.y); pk.u[6] = f2bf(v1.z); pk.u[7] = f2bf(v1.w);
      *(uint4*)&sA[arow * 40 + ako] = pk.qq;
    }
#pragma unroll
    for (int i = 0; i < 8; i++) {
      int c = tid + 256 * i, r = c >> 2, ko = (c & 3) * 8;
      *(uint4*)&sB[r * 40 + ko] = *(const uint4*)&oW2t[(long)r * 512 + kb + ko];
    }
    __syncthreads();
    frag_t af = *(const frag_t*)&sA[(wv * 16 + l15) * 40 + q * 8];
#pragma unroll
    for (int nt = 0; nt < 32; nt++) {
      frag_t bf = *(const frag_t*)&sB[(nt * 16 + l15) * 40 + q * 8];
      acc[nt] = MFMA(af, bf, acc[nt]);
    }
    __syncthreads();
  }
#pragma unroll
  for (int r = 0; r < 4; r++) {
    const long t = t0 + wv * 16 + q * 4 + r;
#pragma unroll
    for (int nt = 0; nt < 32; nt++) {
      int col = nt * 16 + l15;
      float v = acc[nt][r] + ob2[col] + bf2f(xn[t * 512 + col]);
      outp[t * 512 + col] = v;
    }
  }
}

extern "C" void kernel_launch(void* const* d_in, const int* in_sizes, int n_in,
                              void* d_out, int out_size, void* d_ws, size_t ws_size,
                              hipStream_t stream) {
  const float* x    = (const float*)d_in[0];
  const float* ng   = (const float*)d_in[1];
  const float* nbp  = (const float*)d_in[2];
  const float* hW1  = (const float*)d_in[3];
  const float* hb1  = (const float*)d_in[4];
  const float* hlng = (const float*)d_in[5];
  const float* hlnb = (const float*)d_in[6];
  const float* hW2  = (const float*)d_in[7];
  const float* hb2  = (const float*)d_in[8];
  const float* attr = (const float*)d_in[9];
  const float* dyn  = (const float*)d_in[10];
  const float* gW   = (const float*)d_in[11];
  const float* gb   = (const float*)d_in[12];
  const float* oW1  = (const float*)d_in[13];
  const float* ob1  = (const float*)d_in[14];
  const float* olng = (const float*)d_in[15];
  const float* olnb = (const float*)d_in[16];
  const float* oW2  = (const float*)d_in[17];
  const float* ob2  = (const float*)d_in[18];

  char* ws = (char*)d_ws;
  u16*   xn   = (u16*)ws;                   // 67,108,864 B  [65536,512] bf16
  float* gate = (float*)(ws + 67108864);    //  1,048,576 B  [65536,4] f32
  u16*   wT   = (u16*)(ws + 68157440);      //  2,490,368 B  transposed bf16 weights
  u16* hW1t = wT;                // [4][256][512]
  u16* hW2t = wT + 524288;       // [4][128][256]
  u16* dynT = wT + 655360;       // [4][128][128]
  u16* oW1t = wT + 720896;       // [512][512]
  u16* oW2t = wT + 983040;       // [512][512]

  k_tr<<<512, 256, 0, stream>>>(hW1, hW1t, 4, 512, 256);
  k_tr<<<128, 256, 0, stream>>>(hW2, hW2t, 4, 256, 128);
  k_tr<<<64, 256, 0, stream>>>(dyn, dynT, 4, 128, 128);
  k_tr<<<256, 256, 0, stream>>>(oW1, oW1t, 1, 512, 512);
  k_tr<<<256, 256, 0, stream>>>(oW2, oW2t, 1, 512, 512);

  k1_ln_gate<<<16384, 256, 0, stream>>>(x, ng, nbp, gW, gb, xn, gate);

  float* out = (float*)d_out;
  k2_head<<<dim3(1024, 4), 256, 0, stream>>>(xn, hW1t, hb1, hlng, hlnb, hW2t, hb2,
                                             attr, dynT, gate, out);
  k3_mlp1<<<1024, 256, 0, stream>>>(out, oW1t, ob1, olng, olnb, out);
  k4_mlp2<<<1024, 256, 0, stream>>>(out, oW2t, ob2, xn, out);
}

// Round 3
// 851.371 us; speedup vs baseline: 1.1508x; 1.1508x over previous
//
#include <hip/hip_runtime.h>

typedef unsigned short u16;
typedef __bf16 bf16x8 __attribute__((ext_vector_type(8)));
typedef short  s16x8  __attribute__((ext_vector_type(8)));
typedef float  f32x4  __attribute__((ext_vector_type(4)));

// --- builtin operand-type hedge: pick whichever vector type the bf16 MFMA
// builtin accepts on this toolchain.
template <bool B, class T, class F> struct cond_t { using type = T; };
template <class T, class F> struct cond_t<false, T, F> { using type = F; };
template <typename T>
__device__ auto probe_mfma(int)
    -> decltype(__builtin_amdgcn_mfma_f32_16x16x32_bf16(T{}, T{}, f32x4{}, 0, 0, 0), (char)0);
template <typename T> __device__ short probe_mfma(...);
using frag_t = typename cond_t<sizeof(probe_mfma<bf16x8>(0)) == 1, bf16x8, s16x8>::type;
#define MFMA(a, b, c) __builtin_amdgcn_mfma_f32_16x16x32_bf16((a), (b), (c), 0, 0, 0)

__device__ __forceinline__ float bf2f(u16 u) {
  unsigned int x = ((unsigned int)u) << 16; float f; __builtin_memcpy(&f, &x, 4); return f;
}
__device__ __forceinline__ u16 f2bf(float f) {
  unsigned int x; __builtin_memcpy(&x, &f, 4);
  x += 0x7fffu + ((x >> 16) & 1u);  // RNE
  return (u16)(x >> 16);
}
__device__ __forceinline__ float fast_rcp(float x) { return __builtin_amdgcn_rcpf(x); }
__device__ __forceinline__ float tanh_fast(float x) {
  // 1 - 2/(1+e^{2x}); saturates correctly at +-inf
  float t = __expf(2.0f * x);
  return 1.0f - 2.0f * fast_rcp(1.0f + t);
}
__device__ __forceinline__ float gelu_f(float x) {
  // tanh-form GELU (max abs err ~3e-4 vs exact erf form)
  float x3 = x * x * x;
  return 0.5f * x * (1.0f + tanh_fast(0.7978845608028654f * x + 0.035677408136300125f * x3));
}
__device__ __forceinline__ float sigmoid_fast(float x) {
  return fast_rcp(1.0f + __expf(-x));
}

// ---------- weight transpose+cast: dst[b][n][k] (bf16) = src[b][k][n] (f32) ----------
__global__ __launch_bounds__(256) void k_tr(const float* __restrict__ src, u16* __restrict__ dst,
                                            int batch, int K, int N) {
  long KN = (long)K * N;
  long total = (long)batch * KN;
  for (long i = (long)blockIdx.x * blockDim.x + threadIdx.x; i < total;
       i += (long)gridDim.x * blockDim.x) {
    long b = i / KN; long rem = i - b * KN;
    long n = rem / K; long k = rem - n * K;
    dst[i] = f2bf(src[b * KN + k * N + n]);
  }
}

// ---------- K1: LayerNorm(x) -> xn (bf16, ws) ; sigmoid gates -> f32 (ws) ----------
__global__ __launch_bounds__(256) void k1_ln_gate(
    const float* __restrict__ x, const float* __restrict__ ng, const float* __restrict__ nb,
    const float* __restrict__ gW, const float* __restrict__ gb,
    u16* __restrict__ xn, float* __restrict__ gate) {
  const int lane = threadIdx.x & 63;
  const long t = (long)blockIdx.x * 4 + (threadIdx.x >> 6);
  float4 a0 = *(const float4*)(x + t * 512 + lane * 8);
  float4 a1 = *(const float4*)(x + t * 512 + lane * 8 + 4);
  float f[8] = {a0.x, a0.y, a0.z, a0.w, a1.x, a1.y, a1.z, a1.w};
  float s = 0.f, ss = 0.f;
#pragma unroll
  for (int j = 0; j < 8; j++) { s += f[j]; ss += f[j] * f[j]; }
#pragma unroll
  for (int m = 1; m < 64; m <<= 1) { s += __shfl_xor(s, m); ss += __shfl_xor(ss, m); }
  const float mean = s * (1.0f / 512.0f);
  const float rstd = rsqrtf(ss * (1.0f / 512.0f) - mean * mean + 1e-5f);
  float xf[8];
  union { uint4 q; u16 u[8]; } st;
#pragma unroll
  for (int j = 0; j < 8; j++) {
    xf[j] = (f[j] - mean) * rstd * ng[lane * 8 + j] + nb[lane * 8 + j];
    st.u[j] = f2bf(xf[j]);
  }
  *(uint4*)(xn + t * 512 + lane * 8) = st.q;
  for (int h = 0; h < 4; h++) {
    float p = 0.f;
#pragma unroll
    for (int j = 0; j < 8; j++) p += xf[j] * gW[h * 512 + lane * 8 + j];
#pragma unroll
    for (int m = 1; m < 64; m <<= 1) p += __shfl_xor(p, m);
    if (lane == 0) gate[t * 4 + h] = sigmoid_fast(p + gb[h]);
  }
}

// ---------- K2: per (64-token tile, head) fused head pipeline ----------
// LDS overlay plan (peak 44032 B -> 3 blocks/CU):
//   phase1: sA@0 [64][40], sB@5120 [256][40]          (25.6 KB)
//   epi1  : sH@0 [64][264]                            (33.8 KB, over dead sA/sB)
//   phase2: sH@0 + sB2@33792 [128][40]                (44.0 KB peak)
//   phase3: sSt@0 [64][136] (over dead sH), attrF@17408 [8][128] f32,
//           a2@21504 [8] f32, sB2@33792 stays          (44.0 KB peak)
__global__ __launch_bounds__(256, 1) void k2_head(
    const u16* __restrict__ xn, const u16* __restrict__ hW1t, const float* __restrict__ hb1,
    const float* __restrict__ hlng, const float* __restrict__ hlnb,
    const u16* __restrict__ hW2t, const float* __restrict__ hb2,
    const float* __restrict__ attr, const u16* __restrict__ dynT,
    const float* __restrict__ gate, u16* __restrict__ outC) {
  __shared__ __align__(16) char smem[44032];
  u16* sA  = (u16*)(smem);                 // [64][40]
  u16* sB  = (u16*)(smem + 5120);          // [256][40]
  u16* sH  = (u16*)(smem);                 // [64][264]
  u16* sB2 = (u16*)(smem + 33792);         // [128][40]
  u16* sSt = (u16*)(smem);                 // [64][136]
  float* sAttrF = (float*)(smem + 17408);  // [8][128]
  float* sA2    = (float*)(smem + 21504);  // [8]

  const int tid = threadIdx.x;
  const int lane = tid & 63, wv = tid >> 6, q = lane >> 4, l15 = lane & 15;
  const int h = blockIdx.y;
  const long t0 = (long)blockIdx.x * 64;
  const f32x4 vz = {0.f, 0.f, 0.f, 0.f};

  f32x4 acc[16];
#pragma unroll
  for (int i = 0; i < 16; i++) acc[i] = vz;
  const int arow = tid >> 2, ako = (tid & 3) * 8;

  for (int kb = 0; kb < 512; kb += 32) {
    *(uint4*)&sA[arow * 40 + ako] = *(const uint4*)&xn[(t0 + arow) * 512 + kb + ako];
#pragma unroll
    for (int i = 0; i < 4; i++) {
      int c = tid + 256 * i, r = c >> 2, ko = (c & 3) * 8;
      *(uint4*)&sB[r * 40 + ko] = *(const uint4*)&hW1t[((long)h * 256 + r) * 512 + kb + ko];
    }
    __syncthreads();
    frag_t af = *(const frag_t*)&sA[(wv * 16 + l15) * 40 + q * 8];
#pragma unroll
    for (int nt = 0; nt < 16; nt++) {
      frag_t bf = *(const frag_t*)&sB[(nt * 16 + l15) * 40 + q * 8];
      acc[nt] = MFMA(af, bf, acc[nt]);
    }
    __syncthreads();
  }

  {  // bias + LN(256) + gelu -> sH (bf16)
    float bb[16], cg[16], cb[16];
#pragma unroll
    for (int nt = 0; nt < 16; nt++) {
      int col = nt * 16 + l15;
      bb[nt] = hb1[h * 256 + col];
      cg[nt] = hlng[h * 256 + col];
      cb[nt] = hlnb[h * 256 + col];
    }
#pragma unroll
    for (int r = 0; r < 4; r++) {
      float s = 0.f, ss = 0.f;
#pragma unroll
      for (int nt = 0; nt < 16; nt++) { float v = acc[nt][r] + bb[nt]; s += v; ss += v * v; }
#pragma unroll
      for (int m = 1; m < 16; m <<= 1) { s += __shfl_xor(s, m); ss += __shfl_xor(ss, m); }
      float mean = s * (1.f / 256.f);
      float rstd = rsqrtf(ss * (1.f / 256.f) - mean * mean + 1e-5f);
      int row = wv * 16 + q * 4 + r;
#pragma unroll
      for (int nt = 0; nt < 16; nt++) {
        float v = (acc[nt][r] + bb[nt] - mean) * rstd * cg[nt] + cb[nt];
        sH[row * 264 + nt * 16 + l15] = f2bf(gelu_f(v));
      }
    }
  }
  __syncthreads();

  f32x4 acc2[8];
#pragma unroll
  for (int i = 0; i < 8; i++) acc2[i] = vz;
  for (int kb = 0; kb < 256; kb += 32) {
#pragma unroll
    for (int i = 0; i < 2; i++) {
      int c = tid + 256 * i, r = c >> 2, ko = (c & 3) * 8;
      *(uint4*)&sB2[r * 40 + ko] = *(const uint4*)&hW2t[((long)h * 128 + r) * 256 + kb + ko];
    }
    __syncthreads();
    frag_t af = *(const frag_t*)&sH[(wv * 16 + l15) * 264 + kb + q * 8];
#pragma unroll
    for (int nt = 0; nt < 8; nt++) {
      frag_t bf = *(const frag_t*)&sB2[(nt * 16 + l15) * 40 + q * 8];
      acc2[nt] = MFMA(af, bf, acc2[nt]);
    }
    __syncthreads();
  }
#pragma unroll
  for (int nt = 0; nt < 8; nt++) {
    float b2 = hb2[h * 128 + nt * 16 + l15];
#pragma unroll
    for (int r = 0; r < 4; r++) acc2[nt][r] += b2;
  }

  // state -> sSt (bf16, over dead sH); attractors -> LDS f32
#pragma unroll
  for (int nt = 0; nt < 8; nt++)
#pragma unroll
    for (int r = 0; r < 4; r++)
      sSt[(wv * 16 + q * 4 + r) * 136 + nt * 16 + l15] = f2bf(acc2[nt][r]);
#pragma unroll
  for (int i = 0; i < 4; i++) { int c = tid + 256 * i; sAttrF[c] = attr[h * 1024 + c]; }
  __syncthreads();
  if (tid < 64) {  // a2[a] = ||attr_a||^2, 8 lanes per attractor
    int a = tid >> 3, j = tid & 7;
    float s = 0.f;
#pragma unroll
    for (int d2 = 0; d2 < 16; d2++) { float v = sAttrF[a * 128 + j * 16 + d2]; s += v * v; }
#pragma unroll
    for (int m = 1; m < 8; m <<= 1) s += __shfl_xor(s, m);
    if (j == 0) sA2[a] = s;
  }
  __syncthreads();

  f32x4 dacc[8];
#pragma unroll
  for (int i = 0; i < 8; i++) dacc[i] = vz;
  for (int kb = 0; kb < 128; kb += 32) {
#pragma unroll
    for (int i = 0; i < 2; i++) {
      int c = tid + 256 * i, r = c >> 2, ko = (c & 3) * 8;
      *(uint4*)&sB2[r * 40 + ko] = *(const uint4*)&dynT[((long)h * 128 + r) * 128 + kb + ko];
    }
    __syncthreads();
    frag_t af = *(const frag_t*)&sSt[(wv * 16 + l15) * 136 + kb + q * 8];
#pragma unroll
    for (int nt = 0; nt < 8; nt++) {
      frag_t bf = *(const frag_t*)&sB2[(nt * 16 + l15) * 40 + q * 8];
      dacc[nt] = MFMA(af, bf, dacc[nt]);
    }
    __syncthreads();
  }

  const float dscale = 0.088388347648318447f;  // 1/sqrt(128)
#pragma unroll
  for (int r = 0; r < 4; r++) {
    const long t = t0 + wv * 16 + q * 4 + r;
    float s2v = 0.f;
#pragma unroll
    for (int nt = 0; nt < 8; nt++) s2v += acc2[nt][r] * acc2[nt][r];
#pragma unroll
    for (int m = 1; m < 16; m <<= 1) s2v += __shfl_xor(s2v, m);
    float lg[8]; float mx = -3.0e38f;
#pragma unroll
    for (int a = 0; a < 8; a++) {
      float sa = 0.f;
#pragma unroll
      for (int nt = 0; nt < 8; nt++) sa += acc2[nt][r] * sAttrF[a * 128 + nt * 16 + l15];
#pragma unroll
      for (int m = 1; m < 16; m <<= 1) sa += __shfl_xor(sa, m);
      float dist = sqrtf(fmaxf(s2v + sA2[a] - 2.0f * sa, 0.0f));
      lg[a] = -dist * dscale;
      mx = fmaxf(mx, lg[a]);
    }
    float den = 0.f;
#pragma unroll
    for (int a = 0; a < 8; a++) { lg[a] = __expf(lg[a] - mx); den += lg[a]; }
    const float rden = fast_rcp(den);
    const float g01 = gate[t * 4 + h] * 0.1f;
#pragma unroll
    for (int nt = 0; nt < 8; nt++) {
      int col = nt * 16 + l15;
      float ai = 0.f;
#pragma unroll
      for (int a = 0; a < 8; a++) ai += lg[a] * sAttrF[a * 128 + col];
      ai *= rden;
      float stv = acc2[nt][r];
      float ho = stv + g01 * (ai - stv + tanh_fast(dacc[nt][r]));
      // interleaved d_out rows: comb row t lives at u16 offset t*1024
      outC[t * 1024 + h * 128 + col] = f2bf(ho);
    }
  }
}

// ---------- K3: o1 = gelu(LN(comb @ oW1 + ob1)) ; comb/o1 interleaved in d_out ----------
__global__ __launch_bounds__(256, 1) void k3_mlp1(
    const u16* __restrict__ inp, const u16* __restrict__ oW1t,
    const float* __restrict__ ob1, const float* __restrict__ olng, const float* __restrict__ olnb,
    u16* __restrict__ outp) {
  __shared__ __align__(16) char smem[46080];
  u16* sA = (u16*)smem;            // [64][40]
  u16* sB = (u16*)(smem + 5120);   // [512][40]
  const int tid = threadIdx.x, lane = tid & 63, wv = tid >> 6, q = lane >> 4, l15 = lane & 15;
  const long t0 = (long)blockIdx.x * 64;
  const f32x4 vz = {0.f, 0.f, 0.f, 0.f};
  f32x4 acc[32];
#pragma unroll
  for (int i = 0; i < 32; i++) acc[i] = vz;
  const int arow = tid >> 2, ako = (tid & 3) * 8;
  for (int kb = 0; kb < 512; kb += 32) {
    *(uint4*)&sA[arow * 40 + ako] = *(const uint4*)&inp[(t0 + arow) * 1024 + kb + ako];
#pragma unroll
    for (int i = 0; i < 8; i++) {
      int c = tid + 256 * i, r = c >> 2, ko = (c & 3) * 8;
      *(uint4*)&sB[r * 40 + ko] = *(const uint4*)&oW1t[(long)r * 512 + kb + ko];
    }
    __syncthreads();
    frag_t af = *(const frag_t*)&sA[(wv * 16 + l15) * 40 + q * 8];
#pragma unroll
    for (int nt = 0; nt < 32; nt++) {
      frag_t bf = *(const frag_t*)&sB[(nt * 16 + l15) * 40 + q * 8];
      acc[nt] = MFMA(af, bf, acc[nt]);
    }
    __syncthreads();
  }
  float bb[32];
#pragma unroll
  for (int nt = 0; nt < 32; nt++) bb[nt] = ob1[nt * 16 + l15];
#pragma unroll
  for (int r = 0; r < 4; r++) {
    float s = 0.f, ss = 0.f;
#pragma unroll
    for (int nt = 0; nt < 32; nt++) { float v = acc[nt][r] + bb[nt]; s += v; ss += v * v; }
#pragma unroll
    for (int m = 1; m < 16; m <<= 1) { s += __shfl_xor(s, m); ss += __shfl_xor(ss, m); }
    float mean = s * (1.f / 512.f);
    float rstd = rsqrtf(ss * (1.f / 512.f) - mean * mean + 1e-5f);
    const long t = t0 + wv * 16 + q * 4 + r;
#pragma unroll
    for (int nt = 0; nt < 32; nt++) {
      int col = nt * 16 + l15;
      float v = (acc[nt][r] + bb[nt] - mean) * rstd * olng[col] + olnb[col];
      outp[t * 1024 + col] = f2bf(gelu_f(v));
    }
  }
}

// ---------- K4: out = xn + o1 @ oW2 + ob2 ; o1 bf16 (interleaved), out f32 ----------
__global__ __launch_bounds__(256, 1) void k4_mlp2(
    const u16* __restrict__ inp, const u16* __restrict__ oW2t,
    const float* __restrict__ ob2, const u16* __restrict__ xn,
    float* __restrict__ outp) {
  __shared__ __align__(16) char smem[46080];
  u16* sA = (u16*)smem;
  u16* sB = (u16*)(smem + 5120);
  const int tid = threadIdx.x, lane = tid & 63, wv = tid >> 6, q = lane >> 4, l15 = lane & 15;
  const long t0 = (long)blockIdx.x * 64;
  const f32x4 vz = {0.f, 0.f, 0.f, 0.f};
  f32x4 acc[32];
#pragma unroll
  for (int i = 0; i < 32; i++) acc[i] = vz;
  const int arow = tid >> 2, ako = (tid & 3) * 8;
  for (int kb = 0; kb < 512; kb += 32) {
    *(uint4*)&sA[arow * 40 + ako] = *(const uint4*)&inp[(t0 + arow) * 1024 + kb + ako];
#pragma unroll
    for (int i = 0; i < 8; i++) {
      int c = tid + 256 * i, r = c >> 2, ko = (c & 3) * 8;
      *(uint4*)&sB[r * 40 + ko] = *(const uint4*)&oW2t[(long)r * 512 + kb + ko];
    }
    __syncthreads();
    frag_t af = *(const frag_t*)&sA[(wv * 16 + l15) * 40 + q * 8];
#pragma unroll
    for (int nt = 0; nt < 32; nt++) {
      frag_t bf = *(const frag_t*)&sB[(nt * 16 + l15) * 40 + q * 8];
      acc[nt] = MFMA(af, bf, acc[nt]);
    }
    __syncthreads();
  }
#pragma unroll
  for (int r = 0; r < 4; r++) {
    const long t = t0 + wv * 16 + q * 4 + r;
#pragma unroll
    for (int nt = 0; nt < 32; nt++) {
      int col = nt * 16 + l15;
      float v = acc[nt][r] + ob2[col] + bf2f(xn[t * 512 + col]);
      outp[t * 512 + col] = v;
    }
  }
}

extern "C" void kernel_launch(void* const* d_in, const int* in_sizes, int n_in,
                              void* d_out, int out_size, void* d_ws, size_t ws_size,
                              hipStream_t stream) {
  const float* x    = (const float*)d_in[0];
  const float* ng   = (const float*)d_in[1];
  const float* nbp  = (const float*)d_in[2];
  const float* hW1  = (const float*)d_in[3];
  const float* hb1  = (const float*)d_in[4];
  const float* hlng = (const float*)d_in[5];
  const float* hlnb = (const float*)d_in[6];
  const float* hW2  = (const float*)d_in[7];
  const float* hb2  = (const float*)d_in[8];
  const float* attr = (const float*)d_in[9];
  const float* dyn  = (const float*)d_in[10];
  const float* gW   = (const float*)d_in[11];
  const float* gb   = (const float*)d_in[12];
  const float* oW1  = (const float*)d_in[13];
  const float* ob1  = (const float*)d_in[14];
  const float* olng = (const float*)d_in[15];
  const float* olnb = (const float*)d_in[16];
  const float* oW2  = (const float*)d_in[17];
  const float* ob2  = (const float*)d_in[18];

  char* ws = (char*)d_ws;
  u16*   xn   = (u16*)ws;                   // 67,108,864 B  [65536,512] bf16
  float* gate = (float*)(ws + 67108864);    //  1,048,576 B  [65536,4] f32
  u16*   wT   = (u16*)(ws + 68157440);      //  2,490,368 B  transposed bf16 weights
  u16* hW1t = wT;                // [4][256][512]
  u16* hW2t = wT + 524288;       // [4][128][256]
  u16* dynT = wT + 655360;       // [4][128][128]
  u16* oW1t = wT + 720896;       // [512][512]
  u16* oW2t = wT + 983040;       // [512][512]

  k_tr<<<512, 256, 0, stream>>>(hW1, hW1t, 4, 512, 256);
  k_tr<<<128, 256, 0, stream>>>(hW2, hW2t, 4, 256, 128);
  k_tr<<<64, 256, 0, stream>>>(dyn, dynT, 4, 128, 128);
  k_tr<<<256, 256, 0, stream>>>(oW1, oW1t, 1, 512, 512);
  k_tr<<<256, 256, 0, stream>>>(oW2, oW2t, 1, 512, 512);

  k1_ln_gate<<<16384, 256, 0, stream>>>(x, ng, nbp, gW, gb, xn, gate);

  // d_out doubles as bf16 scratch, per-row interleaved:
  //   row t: u16 [t*1024 .. t*1024+512) = comb, [t*1024+512 .. t*1024+1024) = o1
  // k4's f32 writes to row t only touch bytes also indexed by row t -> no
  // cross-block read/write hazard anywhere.
  u16* cb = (u16*)d_out;
  k2_head<<<dim3(1024, 4), 256, 0, stream>>>(xn, hW1t, hb1, hlng, hlnb, hW2t, hb2,
                                             attr, dynT, gate, cb);
  k3_mlp1<<<1024, 256, 0, stream>>>(cb, oW1t, ob1, olng, olnb, cb + 512);
  k4_mlp2<<<1024, 256, 0, stream>>>(cb + 512, oW2t, ob2, xn, (float*)d_out);
}